// Round 2
// baseline (840.071 us; speedup 1.0000x reference)
//
#include <hip/hip_runtime.h>
#include <hip/hip_bf16.h>
#include <math.h>

typedef __hip_bfloat16 BF;

#define NNODES 16384
#define LSEQ   512
#define NB     32
#define HID    768
#define NV     8192

__device__ __forceinline__ float b2f(BF x) { return __bfloat162float(x); }
__device__ __forceinline__ float lrelu(float x) { return x > 0.f ? x : 0.2f * x; }
// dtype-agnostic load: f32 flag picks float vs bf16 interpretation
__device__ __forceinline__ float ldf(const void* p, size_t i, int f32) {
  return f32 ? ((const float*)p)[i] : __bfloat162float(((const BF*)p)[i]);
}

// ---------------- dtype detect: edge_matrix is uniform[0,1) -> bf16 halfwords never
// have the sign bit set; f32 low-mantissa halfwords (even indices) are random bits.
__global__ void k_detect(const unsigned short* __restrict__ em16, int* __restrict__ flag) {
  if (threadIdx.x == 0) {
    int f = 0;
    for (int i = 0; i < 256; i += 2) f |= (em16[i] >> 15) & 1;
    *flag = f;
  }
}

// ---------------- prep: W1 -> f32, v_s = W2 @ att_src2, v_d = W2 @ att_dst2 ----------------
__global__ __launch_bounds__(256) void k_prep(const void* __restrict__ W1,
                                              const void* __restrict__ W2,
                                              const void* __restrict__ att_s2,
                                              const void* __restrict__ att_d2,
                                              const int* __restrict__ flag,
                                              float* __restrict__ w1f,
                                              float* __restrict__ v_s,
                                              float* __restrict__ v_d) {
  int f32 = *flag;
  int g = blockIdx.x * 256 + threadIdx.x;
  if (g < HID * 32) w1f[g] = ldf(W1, g, f32);
  if (blockIdx.x == 96) {
    int t = threadIdx.x;
    if (t < 64) {
      int k = t & 31;
      const void* att = (t < 32) ? att_s2 : att_d2;
      float acc = 0.f;
      for (int c = 0; c < HID; c++) acc += ldf(W2, (size_t)k * HID + c, f32) * ldf(att, c, f32);
      if (t < 32) v_s[k] = acc; else v_d[k] = acc;
    }
  }
}

// ---------------- h1 = features @ W1 ; a_s1/a_d1 per (node, head) ----------------
// grid 512, block 256: 32 rows/block, each thread does 4 output cols of one row.
__global__ __launch_bounds__(256) void k_h1(const void* __restrict__ feat,
                                            const float* __restrict__ w1f,
                                            const void* __restrict__ as1w,
                                            const void* __restrict__ ad1w,
                                            const int* __restrict__ flag,
                                            float* __restrict__ h1,
                                            float* __restrict__ a_s1,
                                            float* __restrict__ a_d1) {
  int f32 = *flag;
  int t = threadIdx.x;
  int row = blockIdx.x * 32 + (t >> 3);
  int c0 = (t & 7) * 4;
  float acc0 = 0.f, acc1 = 0.f, acc2 = 0.f, acc3 = 0.f;
  if (f32) {
    const float* frow = (const float*)feat + (size_t)row * HID;
#pragma unroll 2
    for (int k4 = 0; k4 < HID / 4; k4++) {
      float4 f4 = *(const float4*)(frow + 4 * k4);
      const float4 w0 = *(const float4*)(w1f + (4 * k4 + 0) * 32 + c0);
      const float4 w1 = *(const float4*)(w1f + (4 * k4 + 1) * 32 + c0);
      const float4 w2 = *(const float4*)(w1f + (4 * k4 + 2) * 32 + c0);
      const float4 w3 = *(const float4*)(w1f + (4 * k4 + 3) * 32 + c0);
      acc0 += f4.x * w0.x + f4.y * w1.x + f4.z * w2.x + f4.w * w3.x;
      acc1 += f4.x * w0.y + f4.y * w1.y + f4.z * w2.y + f4.w * w3.y;
      acc2 += f4.x * w0.z + f4.y * w1.z + f4.z * w2.z + f4.w * w3.z;
      acc3 += f4.x * w0.w + f4.y * w1.w + f4.z * w2.w + f4.w * w3.w;
    }
  } else {
    const __hip_bfloat162* frow = (const __hip_bfloat162*)((const BF*)feat + (size_t)row * HID);
#pragma unroll 4
    for (int k2 = 0; k2 < HID / 2; k2++) {
      float2 f2 = __bfloat1622float2(frow[k2]);
      const float4 wa = *(const float4*)(w1f + (2 * k2) * 32 + c0);
      const float4 wb = *(const float4*)(w1f + (2 * k2 + 1) * 32 + c0);
      acc0 += f2.x * wa.x + f2.y * wb.x;
      acc1 += f2.x * wa.y + f2.y * wb.y;
      acc2 += f2.x * wa.z + f2.y * wb.z;
      acc3 += f2.x * wa.w + f2.y * wb.w;
    }
  }
  *(float4*)(h1 + (size_t)row * 32 + c0) = make_float4(acc0, acc1, acc2, acc3);
  float as = acc0 * ldf(as1w, c0, f32) + acc1 * ldf(as1w, c0 + 1, f32) +
             acc2 * ldf(as1w, c0 + 2, f32) + acc3 * ldf(as1w, c0 + 3, f32);
  float ad = acc0 * ldf(ad1w, c0, f32) + acc1 * ldf(ad1w, c0 + 1, f32) +
             acc2 * ldf(ad1w, c0 + 2, f32) + acc3 * ldf(ad1w, c0 + 3, f32);
  as += __shfl_xor(as, 1, 64); as += __shfl_xor(as, 2, 64);
  ad += __shfl_xor(ad, 1, 64); ad += __shfl_xor(ad, 2, 64);
  if ((t & 3) == 0) {
    int h = (t >> 2) & 1;
    a_s1[row * 2 + h] = as;
    a_d1[row * 2 + h] = ad;
  }
}

// ---------------- conv1 attention stencil + relu -> x2 ; a_s2/a_d2 via v_s/v_d ----------------
__global__ __launch_bounds__(256) void k_x2(const float* __restrict__ h1,
                                            const float* __restrict__ a_s1,
                                            const float* __restrict__ a_d1,
                                            const int* __restrict__ src_tok,
                                            const int* __restrict__ oth_tok,
                                            const void* __restrict__ em,
                                            const void* __restrict__ b1,
                                            const float* __restrict__ v_s,
                                            const float* __restrict__ v_d,
                                            const int* __restrict__ flag,
                                            float* __restrict__ x2,
                                            float* __restrict__ a_s2,
                                            float* __restrict__ a_d2) {
  int f32 = *flag;
  int t = threadIdx.x;
  int c = t & 31, nl = t >> 5;
  int branch = blockIdx.x >> 11;
  int row = ((blockIdx.x & 2047) << 3) + nl;
  const int* tok = branch ? oth_tok : src_tok;
  int p = row & (LSEQ - 1);
  bool has_l = (p > 0), has_r = (p < LSEQ - 1);
  int h = c >> 4;
  float adi = a_d1[row * 2 + h];
  float e_self = lrelu(a_s1[row * 2 + h] + adi);
  float e_l = -1e30f, e_r = -1e30f, ew_l = 0.f, ew_r = 0.f;
  int ti = tok[row];
  if (has_l) {
    e_l = lrelu(a_s1[(row - 1) * 2 + h] + adi);
    ew_l = ldf(em, (size_t)tok[row - 1] * NV + ti, f32);
  }
  if (has_r) {
    e_r = lrelu(a_s1[(row + 1) * 2 + h] + adi);
    ew_r = ldf(em, (size_t)tok[row + 1] * NV + ti, f32);
  }
  float m = fmaxf(e_self, fmaxf(e_l, e_r));
  float x_self = expf(e_self - m);
  float x_l = has_l ? expf(e_l - m) : 0.f;
  float x_r = has_r ? expf(e_r - m) : 0.f;
  float den = x_self + x_l + x_r + 1e-16f;
  float val = (x_self / den) * h1[(size_t)row * 32 + c];
  if (has_l) val += (x_l / den) * ew_l * h1[(size_t)(row - 1) * 32 + c];
  if (has_r) val += (x_r / den) * ew_r * h1[(size_t)(row + 1) * 32 + c];
  val = fmaxf(val + ldf(b1, c, f32), 0.f);
  float* x2b = x2 + (size_t)branch * (NNODES * 32);
  x2b[(size_t)row * 32 + c] = val;
  float as = val * v_s[c];
  float ad = val * v_d[c];
#pragma unroll
  for (int mm = 16; mm >= 1; mm >>= 1) {
    as += __shfl_xor(as, mm, 64);
    ad += __shfl_xor(ad, mm, 64);
  }
  if (c == 0) {
    a_s2[branch * NNODES + row] = as;
    a_d2[branch * NNODES + row] = ad;
  }
}

// ---------------- per-sequence conv2 softmax weights + weighted pool ----------------
__global__ __launch_bounds__(256) void k_pool(const float* __restrict__ x2,
                                              const float* __restrict__ a_s2,
                                              const float* __restrict__ a_d2,
                                              float* __restrict__ pooledx) {
  __shared__ float s_as[LSEQ], s_ad[LSEQ], s_m[LSEQ], s_den[LSEQ], s_w[LSEQ];
  __shared__ float partial[8][32];
  int t = threadIdx.x;
  int branch = blockIdx.x >> 5;
  int batch = blockIdx.x & 31;
  size_t base = (size_t)branch * NNODES + (size_t)batch * LSEQ;
  for (int p = t; p < LSEQ; p += 256) {
    s_as[p] = a_s2[base + p];
    s_ad[p] = a_d2[base + p];
  }
  __syncthreads();
  for (int p = t; p < LSEQ; p += 256) {
    float adi = s_ad[p];
    float e_self = lrelu(s_as[p] + adi);
    float e_l = (p > 0) ? lrelu(s_as[p - 1] + adi) : -1e30f;
    float e_r = (p < LSEQ - 1) ? lrelu(s_as[p + 1] + adi) : -1e30f;
    float m = fmaxf(e_self, fmaxf(e_l, e_r));
    float den = expf(e_self - m) + ((p > 0) ? expf(e_l - m) : 0.f) +
                ((p < LSEQ - 1) ? expf(e_r - m) : 0.f) + 1e-16f;
    s_m[p] = m;
    s_den[p] = den;
  }
  __syncthreads();
  for (int p = t; p < LSEQ; p += 256) {
    float asp = s_as[p];
    float w = expf(lrelu(asp + s_ad[p]) - s_m[p]) / s_den[p];
    if (p > 0)        w += expf(lrelu(asp + s_ad[p - 1]) - s_m[p - 1]) / s_den[p - 1];
    if (p < LSEQ - 1) w += expf(lrelu(asp + s_ad[p + 1]) - s_m[p + 1]) / s_den[p + 1];
    s_w[p] = w;
  }
  __syncthreads();
  int c = t & 31, g = t >> 5;
  const float* x2b = x2 + base * 32;
  float acc = 0.f;
  for (int p = g; p < LSEQ; p += 8) acc += s_w[p] * x2b[(size_t)p * 32 + c];
  partial[g][c] = acc;
  __syncthreads();
  if (t < 32) {
    float s = 0.f;
#pragma unroll
    for (int gg = 0; gg < 8; gg++) s += partial[gg][t];
    pooledx[blockIdx.x * 32 + t] = s * (1.f / (float)LSEQ);
  }
}

// ---------------- head: pooled@W2+b2 -> tanh(@Wo1+bo1) -> @Wo2+bo2 ----------------
__global__ __launch_bounds__(256) void k_head(const float* __restrict__ pooledx,
                                              const void* __restrict__ W2,
                                              const void* __restrict__ b2,
                                              const void* __restrict__ Wo1,
                                              const void* __restrict__ bo1,
                                              const void* __restrict__ Wo2,
                                              const void* __restrict__ bo2,
                                              const int* __restrict__ flag,
                                              float* __restrict__ outrow,
                                              float* __restrict__ logitsbuf,
                                              float* __restrict__ rownorm,
                                              void* __restrict__ d_out) {
  __shared__ float s_px[32];
  __shared__ float s_pooled[HID];
  __shared__ float s_out[HID];
  __shared__ float s_np[4];
  int f32 = *flag;
  int t = threadIdx.x;
  int bidx = blockIdx.x;
  if (t < 32) s_px[t] = pooledx[bidx * 32 + t];
  __syncthreads();
  for (int c = t; c < HID; c += 256) {
    float acc = ldf(b2, c, f32);
#pragma unroll
    for (int k = 0; k < 32; k++) acc += s_px[k] * ldf(W2, (size_t)k * HID + c, f32);
    s_pooled[c] = acc;
  }
  __syncthreads();
  float nsum = 0.f;
  {
    float a0 = ldf(bo1, t, f32), a1 = ldf(bo1, t + 256, f32), a2 = ldf(bo1, t + 512, f32);
    for (int k = 0; k < HID; k++) {
      float pk = s_pooled[k];
      size_t rb = (size_t)k * HID;
      a0 += pk * ldf(Wo1, rb + t, f32);
      a1 += pk * ldf(Wo1, rb + t + 256, f32);
      a2 += pk * ldf(Wo1, rb + t + 512, f32);
    }
    float o0 = tanhf(a0), o1 = tanhf(a1), o2 = tanhf(a2);
    s_out[t] = o0; s_out[t + 256] = o1; s_out[t + 512] = o2;
    outrow[(size_t)bidx * HID + t] = o0;
    outrow[(size_t)bidx * HID + t + 256] = o1;
    outrow[(size_t)bidx * HID + t + 512] = o2;
    nsum = o0 * o0 + o1 * o1 + o2 * o2;
  }
#pragma unroll
  for (int mm = 32; mm >= 1; mm >>= 1) nsum += __shfl_xor(nsum, mm, 64);
  if ((t & 63) == 0) s_np[t >> 6] = nsum;
  __syncthreads();
  if (t == 0) rownorm[bidx] = fmaxf(sqrtf(s_np[0] + s_np[1] + s_np[2] + s_np[3]), 1e-8f);
  if (t < 10) {
    float acc = ldf(bo2, t, f32);
    for (int k = 0; k < HID; k++) acc += s_out[k] * ldf(Wo2, (size_t)k * 10 + t, f32);
    logitsbuf[bidx * 10 + t] = acc;
    if (bidx < 32) {
      if (f32) ((float*)d_out)[1 + bidx * 10 + t] = acc;
      else ((BF*)d_out)[1 + bidx * 10 + t] = __float2bfloat16(acc);
    }
  }
}

// ---------------- SimCSE similarity matrix ----------------
__global__ __launch_bounds__(256) void k_sim(const float* __restrict__ outrow,
                                             const float* __restrict__ rownorm,
                                             float* __restrict__ simbuf) {
  __shared__ float s_pr[HID];
  __shared__ float s_part[4];
  int t = threadIdx.x;
  int r = blockIdx.x;
  int ir = (r & 1) * 32 + (r >> 1);
  for (int k = t; k < HID; k += 256) s_pr[k] = outrow[(size_t)ir * HID + k];
  __syncthreads();
  float nr = rownorm[ir];
  for (int q = 0; q < 64; q++) {
    int iq = (q & 1) * 32 + (q >> 1);
    const float* pq = outrow + (size_t)iq * HID;
    float s = 0.f;
    for (int k = t; k < HID; k += 256) s += s_pr[k] * pq[k];
#pragma unroll
    for (int mm = 32; mm >= 1; mm >>= 1) s += __shfl_xor(s, mm, 64);
    if ((t & 63) == 0) s_part[t >> 6] = s;
    __syncthreads();
    if (t == 0) {
      float tot = (s_part[0] + s_part[1] + s_part[2] + s_part[3]) / (nr * rownorm[iq]);
      if (q == r) tot -= 1e12f;
      simbuf[r * 64 + q] = tot * 20.f;
    }
    __syncthreads();
  }
}

// ---------------- final losses ----------------
__global__ void k_loss(const float* __restrict__ logitsbuf, const int* __restrict__ label,
                       const float* __restrict__ simbuf, const int* __restrict__ flag,
                       void* __restrict__ d_out) {
  __shared__ float s_nll[64], s_sl[64];
  int t = threadIdx.x;  // 64 threads
  {
    const float* lg = logitsbuf + t * 10;
    float m = lg[0];
    for (int j = 1; j < 10; j++) m = fmaxf(m, lg[j]);
    float s = 0.f;
    for (int j = 0; j < 10; j++) s += expf(lg[j] - m);
    s_nll[t] = -(lg[label[t & 31]] - (m + logf(s)));
  }
  {
    const float* row = simbuf + t * 64;
    float m = row[0];
    for (int q = 1; q < 64; q++) m = fmaxf(m, row[q]);
    float s = 0.f;
    for (int q = 0; q < 64; q++) s += expf(row[q] - m);
    s_sl[t] = -(row[t ^ 1] - (m + logf(s)));
  }
  __syncthreads();
  if (t == 0) {
    float l = 0.f, ol = 0.f, sl = 0.f;
    for (int i = 0; i < 32; i++) { l += s_nll[i]; ol += s_nll[32 + i]; }
    for (int i = 0; i < 64; i++) sl += s_sl[i];
    float tot = l / 32.f + ol / 32.f + sl / 64.f;
    if (*flag) ((float*)d_out)[0] = tot;
    else ((BF*)d_out)[0] = __float2bfloat16(tot);
  }
}

extern "C" void kernel_launch(void* const* d_in, const int* in_sizes, int n_in,
                              void* d_out, int out_size, void* d_ws, size_t ws_size,
                              hipStream_t stream) {
  const int* src   = (const int*)d_in[0];
  const int* oth   = (const int*)d_in[1];
  const int* label = (const int*)d_in[2];
  const void* feat = d_in[3];
  const void* em   = d_in[4];
  const void* W1   = d_in[5];
  const void* as1  = d_in[6];
  const void* ad1  = d_in[7];
  const void* b1   = d_in[8];
  const void* W2   = d_in[9];
  const void* as2  = d_in[10];
  const void* ad2  = d_in[11];
  const void* b2   = d_in[12];
  const void* Wo1  = d_in[13];
  const void* bo1  = d_in[14];
  const void* Wo2  = d_in[15];
  const void* bo2  = d_in[16];

  float* ws = (float*)d_ws;
  float* h1       = ws;                 // 524288
  float* a_s1     = ws + 524288;        // 32768
  float* a_d1     = ws + 557056;        // 32768
  float* v_s      = ws + 589824;        // 32
  float* v_d      = ws + 589856;        // 32
  float* w1f      = ws + 589888;        // 24576
  float* x2       = ws + 614464;        // 1048576 (2 branches)
  float* a_s2     = ws + 1663040;       // 32768
  float* a_d2     = ws + 1695808;       // 32768
  float* pooledx  = ws + 1728576;       // 2048
  float* outrow   = ws + 1730624;       // 49152
  float* logitsbuf= ws + 1779776;       // 640
  float* rownorm  = ws + 1780416;       // 64
  float* simbuf   = ws + 1780480;       // 4096
  int*   flag     = (int*)(ws + 1784576);

  k_detect<<<1, 64, 0, stream>>>((const unsigned short*)em, flag);
  k_prep<<<97, 256, 0, stream>>>(W1, W2, as2, ad2, flag, w1f, v_s, v_d);
  k_h1<<<512, 256, 0, stream>>>(feat, w1f, as1, ad1, flag, h1, a_s1, a_d1);
  k_x2<<<4096, 256, 0, stream>>>(h1, a_s1, a_d1, src, oth, em, b1, v_s, v_d, flag, x2, a_s2, a_d2);
  k_pool<<<64, 256, 0, stream>>>(x2, a_s2, a_d2, pooledx);
  k_head<<<64, 256, 0, stream>>>(pooledx, W2, b2, Wo1, bo1, Wo2, bo2, flag, outrow, logitsbuf, rownorm, d_out);
  k_sim<<<64, 256, 0, stream>>>(outrow, rownorm, simbuf);
  k_loss<<<1, 64, 0, stream>>>(logitsbuf, label, simbuf, flag, d_out);
}

// Round 3
// 509.400 us; speedup vs baseline: 1.6491x; 1.6491x over previous
//
#include <hip/hip_runtime.h>
#include <hip/hip_bf16.h>
#include <math.h>

typedef __hip_bfloat16 BF;

#define NNODES 16384
#define LSEQ   512
#define NB     32
#define HID    768
#define NV     8192

using frag  = __attribute__((ext_vector_type(8))) short;  // 8 bf16
using f32x4 = __attribute__((ext_vector_type(4))) float;

__device__ __forceinline__ float b2f(BF x) { return __bfloat162float(x); }
__device__ __forceinline__ float lrelu(float x) { return x > 0.f ? x : 0.2f * x; }
__device__ __forceinline__ float ldf(const void* p, size_t i, int f32) {
  return f32 ? ((const float*)p)[i] : __bfloat162float(((const BF*)p)[i]);
}
__device__ __forceinline__ unsigned short f2bfbits(float x) {
  __hip_bfloat16 h = __float2bfloat16(x);
  union { __hip_bfloat16 b; unsigned short u; } v; v.b = h; return v.u;
}

// ---------------- dtype detect: parallel, one wave ----------------
__global__ void k_detect(const unsigned short* __restrict__ em16, int* __restrict__ flag) {
  int t = threadIdx.x;  // 64
  int bit = (em16[2 * t] >> 15) & 1;
  unsigned long long b = __ballot(bit != 0);
  if (t == 0) *flag = (b != 0ULL) ? 1 : 0;
}

// ---------------- prep: W1^T -> bf16 [32][768]; v_s/v_d = W2 @ att_{src,dst}2 ----------------
__global__ __launch_bounds__(256) void k_prep(const void* __restrict__ W1,
                                              const void* __restrict__ W2,
                                              const void* __restrict__ att_s2,
                                              const void* __restrict__ att_d2,
                                              const int* __restrict__ flag,
                                              unsigned short* __restrict__ w1t,
                                              float* __restrict__ v_s,
                                              float* __restrict__ v_d) {
  __shared__ float part[4][32];
  int f32 = *flag;
  int t = threadIdx.x;
  if (blockIdx.x < 96) {  // transpose W1 [768][32] -> w1t [32][768] bf16
    int g = blockIdx.x * 256 + t;          // g = c*768 + k
    int c = g / 768, k = g - c * 768;
    unsigned short us = f32 ? f2bfbits(((const float*)W1)[(size_t)k * 32 + c])
                            : ((const unsigned short*)W1)[(size_t)k * 32 + c];
    w1t[g] = us;
  } else {
    const void* att = (blockIdx.x == 96) ? att_s2 : att_d2;
    float* dst = (blockIdx.x == 96) ? v_s : v_d;
    int k = t & 31, g = t >> 5;
    float acc = 0.f;
    for (int c = g * 96; c < g * 96 + 96; c++)
      acc += ldf(W2, (size_t)k * HID + c, f32) * ldf(att, c, f32);
    acc += __shfl_xor(acc, 32, 64);
    if ((t & 63) < 32) part[t >> 6][k] = acc;
    __syncthreads();
    if (t < 32) dst[t] = part[0][t] + part[1][t] + part[2][t] + part[3][t];
  }
}

// ---------------- h1 = feat @ W1 via MFMA ; fused a_s1/a_d1 ----------------
// 256 blocks x 4 waves; wave handles 16 rows x 32 cols, K=768.
__global__ __launch_bounds__(256) void k_h1(const void* __restrict__ feat,
                                            const unsigned short* __restrict__ w1t,
                                            const void* __restrict__ as1w,
                                            const void* __restrict__ ad1w,
                                            const int* __restrict__ flag,
                                            float* __restrict__ h1,
                                            float* __restrict__ a_s1,
                                            float* __restrict__ a_d1) {
  int f32 = *flag;
  int t = threadIdx.x;
  int lane = t & 63, w = t >> 6;
  int r0 = blockIdx.x * 64 + w * 16;
  int m = lane & 15, q = lane >> 4;
  f32x4 acc0 = {0.f, 0.f, 0.f, 0.f}, acc1 = {0.f, 0.f, 0.f, 0.f};
  const unsigned short* b0p = w1t + (size_t)m * HID + q * 8;
  const unsigned short* b1p = w1t + (size_t)(16 + m) * HID + q * 8;
  if (!f32) {
    const unsigned short* arow = (const unsigned short*)feat + (size_t)(r0 + m) * HID + q * 8;
#pragma unroll 4
    for (int kk = 0; kk < 24; kk++) {
      frag a  = *(const frag*)(arow + kk * 32);
      frag b0 = *(const frag*)(b0p + kk * 32);
      frag b1 = *(const frag*)(b1p + kk * 32);
      acc0 = __builtin_amdgcn_mfma_f32_16x16x32_bf16(a, b0, acc0, 0, 0, 0);
      acc1 = __builtin_amdgcn_mfma_f32_16x16x32_bf16(a, b1, acc1, 0, 0, 0);
    }
  } else {
    const float* arow = (const float*)feat + (size_t)(r0 + m) * HID + q * 8;
    for (int kk = 0; kk < 24; kk++) {
      frag a;
#pragma unroll
      for (int j = 0; j < 8; j++) a[j] = (short)f2bfbits(arow[kk * 32 + j]);
      frag b0 = *(const frag*)(b0p + kk * 32);
      frag b1 = *(const frag*)(b1p + kk * 32);
      acc0 = __builtin_amdgcn_mfma_f32_16x16x32_bf16(a, b0, acc0, 0, 0, 0);
      acc1 = __builtin_amdgcn_mfma_f32_16x16x32_bf16(a, b1, acc1, 0, 0, 0);
    }
  }
  // C layout: col = lane&15 (within tile), row = (lane>>4)*4 + reg
  float asw0 = ldf(as1w, m, f32), asw1 = ldf(as1w, 16 + m, f32);
  float adw0 = ldf(ad1w, m, f32), adw1 = ldf(ad1w, 16 + m, f32);
  float v_as0[4], v_as1[4], v_ad0[4], v_ad1[4];
#pragma unroll
  for (int r = 0; r < 4; r++) {
    int row = r0 + q * 4 + r;
    h1[(size_t)row * 32 + m] = acc0[r];
    h1[(size_t)row * 32 + 16 + m] = acc1[r];
    v_as0[r] = acc0[r] * asw0; v_as1[r] = acc1[r] * asw1;
    v_ad0[r] = acc0[r] * adw0; v_ad1[r] = acc1[r] * adw1;
  }
#pragma unroll
  for (int d = 1; d < 16; d <<= 1) {
#pragma unroll
    for (int r = 0; r < 4; r++) {
      v_as0[r] += __shfl_xor(v_as0[r], d, 64);
      v_as1[r] += __shfl_xor(v_as1[r], d, 64);
      v_ad0[r] += __shfl_xor(v_ad0[r], d, 64);
      v_ad1[r] += __shfl_xor(v_ad1[r], d, 64);
    }
  }
  if (m == 0) {
#pragma unroll
    for (int r = 0; r < 4; r++) {
      int row = r0 + q * 4 + r;
      a_s1[row * 2 + 0] = v_as0[r];
      a_s1[row * 2 + 1] = v_as1[r];
      a_d1[row * 2 + 0] = v_ad0[r];
      a_d1[row * 2 + 1] = v_ad1[r];
    }
  }
}

// ---------------- conv1 attention stencil + relu -> x2 ; a_s2/a_d2 via v_s/v_d ----------------
__global__ __launch_bounds__(256) void k_x2(const float* __restrict__ h1,
                                            const float* __restrict__ a_s1,
                                            const float* __restrict__ a_d1,
                                            const int* __restrict__ src_tok,
                                            const int* __restrict__ oth_tok,
                                            const void* __restrict__ em,
                                            const void* __restrict__ b1,
                                            const float* __restrict__ v_s,
                                            const float* __restrict__ v_d,
                                            const int* __restrict__ flag,
                                            float* __restrict__ x2,
                                            float* __restrict__ a_s2,
                                            float* __restrict__ a_d2) {
  int f32 = *flag;
  int t = threadIdx.x;
  int c = t & 31, nl = t >> 5;
  int branch = blockIdx.x >> 11;
  int row = ((blockIdx.x & 2047) << 3) + nl;
  const int* tok = branch ? oth_tok : src_tok;
  int p = row & (LSEQ - 1);
  bool has_l = (p > 0), has_r = (p < LSEQ - 1);
  int h = c >> 4;
  float adi = a_d1[row * 2 + h];
  float e_self = lrelu(a_s1[row * 2 + h] + adi);
  float e_l = -1e30f, e_r = -1e30f, ew_l = 0.f, ew_r = 0.f;
  int ti = tok[row];
  if (has_l) {
    e_l = lrelu(a_s1[(row - 1) * 2 + h] + adi);
    ew_l = ldf(em, (size_t)tok[row - 1] * NV + ti, f32);
  }
  if (has_r) {
    e_r = lrelu(a_s1[(row + 1) * 2 + h] + adi);
    ew_r = ldf(em, (size_t)tok[row + 1] * NV + ti, f32);
  }
  float m = fmaxf(e_self, fmaxf(e_l, e_r));
  float x_self = expf(e_self - m);
  float x_l = has_l ? expf(e_l - m) : 0.f;
  float x_r = has_r ? expf(e_r - m) : 0.f;
  float den = x_self + x_l + x_r + 1e-16f;
  float val = (x_self / den) * h1[(size_t)row * 32 + c];
  if (has_l) val += (x_l / den) * ew_l * h1[(size_t)(row - 1) * 32 + c];
  if (has_r) val += (x_r / den) * ew_r * h1[(size_t)(row + 1) * 32 + c];
  val = fmaxf(val + ldf(b1, c, f32), 0.f);
  float* x2b = x2 + (size_t)branch * (NNODES * 32);
  x2b[(size_t)row * 32 + c] = val;
  float as = val * v_s[c];
  float ad = val * v_d[c];
#pragma unroll
  for (int mm = 16; mm >= 1; mm >>= 1) {
    as += __shfl_xor(as, mm, 64);
    ad += __shfl_xor(ad, mm, 64);
  }
  if (c == 0) {
    a_s2[branch * NNODES + row] = as;
    a_d2[branch * NNODES + row] = ad;
  }
}

// ---------------- per-sequence conv2 softmax pool + pooled = px@W2+b2 ----------------
__global__ __launch_bounds__(256) void k_pool(const float* __restrict__ x2,
                                              const float* __restrict__ a_s2,
                                              const float* __restrict__ a_d2,
                                              const void* __restrict__ W2,
                                              const void* __restrict__ b2,
                                              const int* __restrict__ flag,
                                              float* __restrict__ pooled) {
  __shared__ float s_as[LSEQ], s_ad[LSEQ], s_m[LSEQ], s_den[LSEQ], s_w[LSEQ];
  __shared__ float partial[8][32];
  __shared__ float s_px[32];
  int f32 = *flag;
  int t = threadIdx.x;
  int branch = blockIdx.x >> 5;
  int batch = blockIdx.x & 31;
  size_t base = (size_t)branch * NNODES + (size_t)batch * LSEQ;
  for (int p = t; p < LSEQ; p += 256) {
    s_as[p] = a_s2[base + p];
    s_ad[p] = a_d2[base + p];
  }
  __syncthreads();
  for (int p = t; p < LSEQ; p += 256) {
    float adi = s_ad[p];
    float e_self = lrelu(s_as[p] + adi);
    float e_l = (p > 0) ? lrelu(s_as[p - 1] + adi) : -1e30f;
    float e_r = (p < LSEQ - 1) ? lrelu(s_as[p + 1] + adi) : -1e30f;
    float m = fmaxf(e_self, fmaxf(e_l, e_r));
    float den = expf(e_self - m) + ((p > 0) ? expf(e_l - m) : 0.f) +
                ((p < LSEQ - 1) ? expf(e_r - m) : 0.f) + 1e-16f;
    s_m[p] = m;
    s_den[p] = den;
  }
  __syncthreads();
  for (int p = t; p < LSEQ; p += 256) {
    float asp = s_as[p];
    float w = expf(lrelu(asp + s_ad[p]) - s_m[p]) / s_den[p];
    if (p > 0)        w += expf(lrelu(asp + s_ad[p - 1]) - s_m[p - 1]) / s_den[p - 1];
    if (p < LSEQ - 1) w += expf(lrelu(asp + s_ad[p + 1]) - s_m[p + 1]) / s_den[p + 1];
    s_w[p] = w;
  }
  __syncthreads();
  {
    int c = t & 31, g = t >> 5;
    const float* x2b = x2 + base * 32;
    float acc = 0.f;
    for (int p = g; p < LSEQ; p += 8) acc += s_w[p] * x2b[(size_t)p * 32 + c];
    partial[g][c] = acc;
  }
  __syncthreads();
  if (t < 32) {
    float s = 0.f;
#pragma unroll
    for (int gg = 0; gg < 8; gg++) s += partial[gg][t];
    s_px[t] = s * (1.f / (float)LSEQ);
  }
  __syncthreads();
  for (int c = t; c < HID; c += 256) {
    float acc = ldf(b2, c, f32);
#pragma unroll
    for (int k = 0; k < 32; k++) acc += s_px[k] * ldf(W2, (size_t)k * HID + c, f32);
    pooled[(size_t)blockIdx.x * HID + c] = acc;
  }
}

// ---------------- out = tanh(pooled @ Wo1 + bo1): 64 rows x 12 col-chunks ----------------
__global__ __launch_bounds__(256) void k_tanh(const float* __restrict__ pooled,
                                              const void* __restrict__ Wo1,
                                              const void* __restrict__ bo1,
                                              const int* __restrict__ flag,
                                              float* __restrict__ outrow) {
  __shared__ float part[4][64];
  int f32 = *flag;
  int t = threadIdx.x;
  int row = blockIdx.x / 12, chunk = blockIdx.x % 12;
  int col = chunk * 64 + (t & 63), kw = t >> 6;
  const float* pr = pooled + (size_t)row * HID + kw * 192;
  float acc = 0.f;
  if (f32) {
    const float* W = (const float*)Wo1 + (size_t)(kw * 192) * HID + col;
#pragma unroll 4
    for (int i = 0; i < 192; i++) acc += pr[i] * W[(size_t)i * HID];
  } else {
    const BF* W = (const BF*)Wo1 + (size_t)(kw * 192) * HID + col;
#pragma unroll 4
    for (int i = 0; i < 192; i++) acc += pr[i] * b2f(W[(size_t)i * HID]);
  }
  part[kw][t & 63] = acc;
  __syncthreads();
  if (t < 64) {
    float s = part[0][t] + part[1][t] + part[2][t] + part[3][t] + ldf(bo1, chunk * 64 + t, f32);
    outrow[(size_t)row * HID + chunk * 64 + t] = tanhf(s);
  }
}

// ---------------- norms + logits ----------------
__global__ __launch_bounds__(256) void k_post(const float* __restrict__ outrow,
                                              const void* __restrict__ Wo2,
                                              const void* __restrict__ bo2,
                                              const int* __restrict__ flag,
                                              float* __restrict__ logitsbuf,
                                              float* __restrict__ rownorm,
                                              void* __restrict__ d_out) {
  __shared__ float s_out[HID];
  __shared__ float s_np[4];
  int f32 = *flag;
  int t = threadIdx.x;
  int b = blockIdx.x;
  float n = 0.f;
  for (int k = t; k < HID; k += 256) {
    float v = outrow[(size_t)b * HID + k];
    s_out[k] = v;
    n += v * v;
  }
#pragma unroll
  for (int d = 32; d >= 1; d >>= 1) n += __shfl_xor(n, d, 64);
  if ((t & 63) == 0) s_np[t >> 6] = n;
  __syncthreads();
  if (t == 0) rownorm[b] = fmaxf(sqrtf(s_np[0] + s_np[1] + s_np[2] + s_np[3]), 1e-8f);
  if (t < 10) {
    float acc = ldf(bo2, t, f32);
#pragma unroll 8
    for (int k = 0; k < HID; k++) acc += s_out[k] * ldf(Wo2, (size_t)k * 10 + t, f32);
    logitsbuf[b * 10 + t] = acc;
    if (b < 32) {
      if (f32) ((float*)d_out)[1 + b * 10 + t] = acc;
      else ((BF*)d_out)[1 + b * 10 + t] = __float2bfloat16(acc);
    }
  }
}

// ---------------- SimCSE similarity: wave-per-q, no barriers in loop ----------------
__global__ __launch_bounds__(256) void k_sim(const float* __restrict__ outrow,
                                             const float* __restrict__ rownorm,
                                             float* __restrict__ simbuf) {
  __shared__ float s_pr[HID];
  int t = threadIdx.x, r = blockIdx.x;
  int ir = (r & 1) * 32 + (r >> 1);
  for (int k = t; k < HID; k += 256) s_pr[k] = outrow[(size_t)ir * HID + k];
  __syncthreads();
  float nr = rownorm[ir];
  int lane = t & 63, w = t >> 6;
  for (int j = 0; j < 16; j++) {
    int qq = 4 * j + w;
    int iq = (qq & 1) * 32 + (qq >> 1);
    const float* pq = outrow + (size_t)iq * HID;
    float s = 0.f;
#pragma unroll
    for (int i = 0; i < 12; i++) s += s_pr[lane + 64 * i] * pq[lane + 64 * i];
#pragma unroll
    for (int d = 32; d >= 1; d >>= 1) s += __shfl_xor(s, d, 64);
    if (lane == 0) {
      float tot = s / (nr * rownorm[iq]);
      if (qq == r) tot -= 1e12f;
      simbuf[r * 64 + qq] = tot * 20.f;
    }
  }
}

// ---------------- final losses ----------------
__global__ void k_loss(const float* __restrict__ logitsbuf, const int* __restrict__ label,
                       const float* __restrict__ simbuf, const int* __restrict__ flag,
                       void* __restrict__ d_out) {
  __shared__ float s_nll[64], s_sl[64];
  int t = threadIdx.x;  // 64 threads
  {
    const float* lg = logitsbuf + t * 10;
    float m = lg[0];
    for (int j = 1; j < 10; j++) m = fmaxf(m, lg[j]);
    float s = 0.f;
    for (int j = 0; j < 10; j++) s += expf(lg[j] - m);
    s_nll[t] = -(lg[label[t & 31]] - (m + logf(s)));
  }
  {
    const float* row = simbuf + t * 64;
    float m = row[0];
    for (int q = 1; q < 64; q++) m = fmaxf(m, row[q]);
    float s = 0.f;
    for (int q = 0; q < 64; q++) s += expf(row[q] - m);
    s_sl[t] = -(row[t ^ 1] - (m + logf(s)));
  }
  __syncthreads();
  if (t == 0) {
    float l = 0.f, ol = 0.f, sl = 0.f;
    for (int i = 0; i < 32; i++) { l += s_nll[i]; ol += s_nll[32 + i]; }
    for (int i = 0; i < 64; i++) sl += s_sl[i];
    float tot = l / 32.f + ol / 32.f + sl / 64.f;
    if (*flag) ((float*)d_out)[0] = tot;
    else ((BF*)d_out)[0] = __float2bfloat16(tot);
  }
}

extern "C" void kernel_launch(void* const* d_in, const int* in_sizes, int n_in,
                              void* d_out, int out_size, void* d_ws, size_t ws_size,
                              hipStream_t stream) {
  const int* src   = (const int*)d_in[0];
  const int* oth   = (const int*)d_in[1];
  const int* label = (const int*)d_in[2];
  const void* feat = d_in[3];
  const void* em   = d_in[4];
  const void* W1   = d_in[5];
  const void* as1  = d_in[6];
  const void* ad1  = d_in[7];
  const void* b1   = d_in[8];
  const void* W2   = d_in[9];
  const void* as2  = d_in[10];
  const void* ad2  = d_in[11];
  const void* b2   = d_in[12];
  const void* Wo1  = d_in[13];
  const void* bo1  = d_in[14];
  const void* Wo2  = d_in[15];
  const void* bo2  = d_in[16];

  float* ws = (float*)d_ws;
  float* h1        = ws;                 // 524288
  float* a_s1      = ws + 524288;        // 32768
  float* a_d1      = ws + 557056;        // 32768
  float* v_s       = ws + 589824;        // 32
  float* v_d       = ws + 589856;        // 32
  float* x2        = ws + 589888;        // 1048576
  float* a_s2      = ws + 1638464;       // 32768
  float* a_d2      = ws + 1671232;       // 32768
  float* pooled    = ws + 1704000;       // 49152
  float* outrow    = ws + 1753152;       // 49152
  float* logitsbuf = ws + 1802304;       // 640
  float* rownorm   = ws + 1802944;       // 64
  float* simbuf    = ws + 1803008;       // 4096
  unsigned short* w1t = (unsigned short*)(ws + 1807104);  // 24576 ushorts
  int*   flag      = (int*)(ws + 1819392);

  k_detect<<<1, 64, 0, stream>>>((const unsigned short*)em, flag);
  k_prep<<<98, 256, 0, stream>>>(W1, W2, as2, ad2, flag, w1t, v_s, v_d);
  k_h1<<<256, 256, 0, stream>>>(feat, w1t, as1, ad1, flag, h1, a_s1, a_d1);
  k_x2<<<4096, 256, 0, stream>>>(h1, a_s1, a_d1, src, oth, em, b1, v_s, v_d, flag, x2, a_s2, a_d2);
  k_pool<<<64, 256, 0, stream>>>(x2, a_s2, a_d2, W2, b2, flag, pooled);
  k_tanh<<<768, 256, 0, stream>>>(pooled, Wo1, bo1, flag, outrow);
  k_post<<<64, 256, 0, stream>>>(outrow, Wo2, bo2, flag, logitsbuf, rownorm, d_out);
  k_sim<<<64, 256, 0, stream>>>(outrow, rownorm, simbuf);
  k_loss<<<1, 64, 0, stream>>>(logitsbuf, label, simbuf, flag, d_out);
}

// Round 4
// 493.853 us; speedup vs baseline: 1.7011x; 1.0315x over previous
//
#include <hip/hip_runtime.h>
#include <hip/hip_bf16.h>
#include <math.h>

typedef __hip_bfloat16 BF;

#define NNODES 16384
#define LSEQ   512
#define NB     32
#define HID    768
#define NV     8192

using frag  = __attribute__((ext_vector_type(8))) short;  // 8 bf16
using f32x4 = __attribute__((ext_vector_type(4))) float;

__device__ __forceinline__ float b2f(BF x) { return __bfloat162float(x); }
__device__ __forceinline__ float lrelu(float x) { return x > 0.f ? x : 0.2f * x; }
__device__ __forceinline__ float ldf(const void* p, size_t i, int f32) {
  return f32 ? ((const float*)p)[i] : __bfloat162float(((const BF*)p)[i]);
}
__device__ __forceinline__ unsigned short f2bfbits(float x) {
  __hip_bfloat16 h = __float2bfloat16(x);
  union { __hip_bfloat16 b; unsigned short u; } v; v.b = h; return v.u;
}
// dtype detect, inline per wave: edge_matrix is uniform[0,1). bf16 halfwords never set
// the sign bit; f32 low-mantissa halfwords (even indices) are random -> a sign bit
// appears with prob 1-2^-64 per wave. Wave-uniform result, no barrier needed.
__device__ __forceinline__ int detect_f32(const unsigned short* __restrict__ em16) {
  int t = threadIdx.x & 63;
  int bit = (em16[2 * t] >> 15) & 1;
  return (__ballot(bit != 0) != 0ULL) ? 1 : 0;
}

// ---------------- prep: W1^T -> bf16 [32][768]; v_s/v_d = W2 @ att_{src,dst}2 ----------------
__global__ __launch_bounds__(256) void k_prep(const void* __restrict__ W1,
                                              const void* __restrict__ W2,
                                              const void* __restrict__ att_s2,
                                              const void* __restrict__ att_d2,
                                              const unsigned short* __restrict__ em16,
                                              unsigned short* __restrict__ w1t,
                                              float* __restrict__ v_s,
                                              float* __restrict__ v_d) {
  __shared__ float part[4][32];
  int f32 = detect_f32(em16);
  int t = threadIdx.x;
  if (blockIdx.x < 96) {  // transpose W1 [768][32] -> w1t [32][768] bf16
    int g = blockIdx.x * 256 + t;          // g = c*768 + k
    int c = g / 768, k = g - c * 768;
    unsigned short us = f32 ? f2bfbits(((const float*)W1)[(size_t)k * 32 + c])
                            : ((const unsigned short*)W1)[(size_t)k * 32 + c];
    w1t[g] = us;
  } else {
    const void* att = (blockIdx.x == 96) ? att_s2 : att_d2;
    float* dst = (blockIdx.x == 96) ? v_s : v_d;
    int k = t & 31, g = t >> 5;
    float acc = 0.f;
    for (int c = g * 96; c < g * 96 + 96; c++)
      acc += ldf(W2, (size_t)k * HID + c, f32) * ldf(att, c, f32);
    acc += __shfl_xor(acc, 32, 64);
    if ((t & 63) < 32) part[t >> 6][k] = acc;
    __syncthreads();
    if (t < 32) dst[t] = part[0][t] + part[1][t] + part[2][t] + part[3][t];
  }
}

// ---------------- h1 = feat @ W1 via MFMA ; fused a_s1/a_d1 ----------------
// 256 blocks x 4 waves; wave handles 16 rows x 32 cols, K=768.
__global__ __launch_bounds__(256) void k_h1(const void* __restrict__ feat,
                                            const unsigned short* __restrict__ w1t,
                                            const void* __restrict__ as1w,
                                            const void* __restrict__ ad1w,
                                            const unsigned short* __restrict__ em16,
                                            float* __restrict__ h1,
                                            float* __restrict__ a_s1,
                                            float* __restrict__ a_d1) {
  int f32 = detect_f32(em16);
  int t = threadIdx.x;
  int lane = t & 63, w = t >> 6;
  int r0 = blockIdx.x * 64 + w * 16;
  int m = lane & 15, q = lane >> 4;
  f32x4 acc0 = {0.f, 0.f, 0.f, 0.f}, acc1 = {0.f, 0.f, 0.f, 0.f};
  const unsigned short* b0p = w1t + (size_t)m * HID + q * 8;
  const unsigned short* b1p = w1t + (size_t)(16 + m) * HID + q * 8;
  if (!f32) {
    const unsigned short* arow = (const unsigned short*)feat + (size_t)(r0 + m) * HID + q * 8;
#pragma unroll 4
    for (int kk = 0; kk < 24; kk++) {
      frag a  = *(const frag*)(arow + kk * 32);
      frag b0 = *(const frag*)(b0p + kk * 32);
      frag b1 = *(const frag*)(b1p + kk * 32);
      acc0 = __builtin_amdgcn_mfma_f32_16x16x32_bf16(a, b0, acc0, 0, 0, 0);
      acc1 = __builtin_amdgcn_mfma_f32_16x16x32_bf16(a, b1, acc1, 0, 0, 0);
    }
  } else {
    const float* arow = (const float*)feat + (size_t)(r0 + m) * HID + q * 8;
    for (int kk = 0; kk < 24; kk++) {
      frag a;
#pragma unroll
      for (int j = 0; j < 8; j++) a[j] = (short)f2bfbits(arow[kk * 32 + j]);
      frag b0 = *(const frag*)(b0p + kk * 32);
      frag b1 = *(const frag*)(b1p + kk * 32);
      acc0 = __builtin_amdgcn_mfma_f32_16x16x32_bf16(a, b0, acc0, 0, 0, 0);
      acc1 = __builtin_amdgcn_mfma_f32_16x16x32_bf16(a, b1, acc1, 0, 0, 0);
    }
  }
  // C layout: col = lane&15 (within tile), row = (lane>>4)*4 + reg
  float asw0 = ldf(as1w, m, f32), asw1 = ldf(as1w, 16 + m, f32);
  float adw0 = ldf(ad1w, m, f32), adw1 = ldf(ad1w, 16 + m, f32);
  float v_as0[4], v_as1[4], v_ad0[4], v_ad1[4];
#pragma unroll
  for (int r = 0; r < 4; r++) {
    int row = r0 + q * 4 + r;
    h1[(size_t)row * 32 + m] = acc0[r];
    h1[(size_t)row * 32 + 16 + m] = acc1[r];
    v_as0[r] = acc0[r] * asw0; v_as1[r] = acc1[r] * asw1;
    v_ad0[r] = acc0[r] * adw0; v_ad1[r] = acc1[r] * adw1;
  }
#pragma unroll
  for (int d = 1; d < 16; d <<= 1) {
#pragma unroll
    for (int r = 0; r < 4; r++) {
      v_as0[r] += __shfl_xor(v_as0[r], d, 64);
      v_as1[r] += __shfl_xor(v_as1[r], d, 64);
      v_ad0[r] += __shfl_xor(v_ad0[r], d, 64);
      v_ad1[r] += __shfl_xor(v_ad1[r], d, 64);
    }
  }
  if (m == 0) {
#pragma unroll
    for (int r = 0; r < 4; r++) {
      int row = r0 + q * 4 + r;
      a_s1[row * 2 + 0] = v_as0[r];
      a_s1[row * 2 + 1] = v_as1[r];
      a_d1[row * 2 + 0] = v_ad0[r];
      a_d1[row * 2 + 1] = v_ad1[r];
    }
  }
}

// ---------------- conv1 attention stencil + relu -> x2 ; a_s2/a_d2 via v_s/v_d ----------------
__global__ __launch_bounds__(256) void k_x2(const float* __restrict__ h1,
                                            const float* __restrict__ a_s1,
                                            const float* __restrict__ a_d1,
                                            const int* __restrict__ src_tok,
                                            const int* __restrict__ oth_tok,
                                            const void* __restrict__ em,
                                            const void* __restrict__ b1,
                                            const float* __restrict__ v_s,
                                            const float* __restrict__ v_d,
                                            float* __restrict__ x2,
                                            float* __restrict__ a_s2,
                                            float* __restrict__ a_d2) {
  int f32 = detect_f32((const unsigned short*)em);
  int t = threadIdx.x;
  int c = t & 31, nl = t >> 5;
  int branch = blockIdx.x >> 11;
  int row = ((blockIdx.x & 2047) << 3) + nl;
  const int* tok = branch ? oth_tok : src_tok;
  int p = row & (LSEQ - 1);
  bool has_l = (p > 0), has_r = (p < LSEQ - 1);
  int h = c >> 4;
  float adi = a_d1[row * 2 + h];
  float e_self = lrelu(a_s1[row * 2 + h] + adi);
  float e_l = -1e30f, e_r = -1e30f, ew_l = 0.f, ew_r = 0.f;
  int ti = tok[row];
  if (has_l) {
    e_l = lrelu(a_s1[(row - 1) * 2 + h] + adi);
    ew_l = ldf(em, (size_t)tok[row - 1] * NV + ti, f32);
  }
  if (has_r) {
    e_r = lrelu(a_s1[(row + 1) * 2 + h] + adi);
    ew_r = ldf(em, (size_t)tok[row + 1] * NV + ti, f32);
  }
  float m = fmaxf(e_self, fmaxf(e_l, e_r));
  float x_self = expf(e_self - m);
  float x_l = has_l ? expf(e_l - m) : 0.f;
  float x_r = has_r ? expf(e_r - m) : 0.f;
  float den = x_self + x_l + x_r + 1e-16f;
  float val = (x_self / den) * h1[(size_t)row * 32 + c];
  if (has_l) val += (x_l / den) * ew_l * h1[(size_t)(row - 1) * 32 + c];
  if (has_r) val += (x_r / den) * ew_r * h1[(size_t)(row + 1) * 32 + c];
  val = fmaxf(val + ldf(b1, c, f32), 0.f);
  float* x2b = x2 + (size_t)branch * (NNODES * 32);
  x2b[(size_t)row * 32 + c] = val;
  float as = val * v_s[c];
  float ad = val * v_d[c];
#pragma unroll
  for (int mm = 16; mm >= 1; mm >>= 1) {
    as += __shfl_xor(as, mm, 64);
    ad += __shfl_xor(ad, mm, 64);
  }
  if (c == 0) {
    a_s2[branch * NNODES + row] = as;
    a_d2[branch * NNODES + row] = ad;
  }
}

// ---------------- per-sequence conv2 softmax pool + pooled = px@W2+b2 ----------------
__global__ __launch_bounds__(256) void k_pool(const float* __restrict__ x2,
                                              const float* __restrict__ a_s2,
                                              const float* __restrict__ a_d2,
                                              const void* __restrict__ W2,
                                              const void* __restrict__ b2,
                                              const unsigned short* __restrict__ em16,
                                              float* __restrict__ pooled) {
  __shared__ float s_as[LSEQ], s_ad[LSEQ], s_m[LSEQ], s_den[LSEQ], s_w[LSEQ];
  __shared__ float partial[8][32];
  __shared__ float s_px[32];
  int f32 = detect_f32(em16);
  int t = threadIdx.x;
  int branch = blockIdx.x >> 5;
  int batch = blockIdx.x & 31;
  size_t base = (size_t)branch * NNODES + (size_t)batch * LSEQ;
  for (int p = t; p < LSEQ; p += 256) {
    s_as[p] = a_s2[base + p];
    s_ad[p] = a_d2[base + p];
  }
  __syncthreads();
  for (int p = t; p < LSEQ; p += 256) {
    float adi = s_ad[p];
    float e_self = lrelu(s_as[p] + adi);
    float e_l = (p > 0) ? lrelu(s_as[p - 1] + adi) : -1e30f;
    float e_r = (p < LSEQ - 1) ? lrelu(s_as[p + 1] + adi) : -1e30f;
    float m = fmaxf(e_self, fmaxf(e_l, e_r));
    float den = expf(e_self - m) + ((p > 0) ? expf(e_l - m) : 0.f) +
                ((p < LSEQ - 1) ? expf(e_r - m) : 0.f) + 1e-16f;
    s_m[p] = m;
    s_den[p] = den;
  }
  __syncthreads();
  for (int p = t; p < LSEQ; p += 256) {
    float asp = s_as[p];
    float w = expf(lrelu(asp + s_ad[p]) - s_m[p]) / s_den[p];
    if (p > 0)        w += expf(lrelu(asp + s_ad[p - 1]) - s_m[p - 1]) / s_den[p - 1];
    if (p < LSEQ - 1) w += expf(lrelu(asp + s_ad[p + 1]) - s_m[p + 1]) / s_den[p + 1];
    s_w[p] = w;
  }
  __syncthreads();
  {
    int c = t & 31, g = t >> 5;
    const float* x2b = x2 + base * 32;
    float acc = 0.f;
    for (int p = g; p < LSEQ; p += 8) acc += s_w[p] * x2b[(size_t)p * 32 + c];
    partial[g][c] = acc;
  }
  __syncthreads();
  if (t < 32) {
    float s = 0.f;
#pragma unroll
    for (int gg = 0; gg < 8; gg++) s += partial[gg][t];
    s_px[t] = s * (1.f / (float)LSEQ);
  }
  __syncthreads();
  for (int c = t; c < HID; c += 256) {
    float acc = ldf(b2, c, f32);
#pragma unroll
    for (int k = 0; k < 32; k++) acc += s_px[k] * ldf(W2, (size_t)k * HID + c, f32);
    pooled[(size_t)blockIdx.x * HID + c] = acc;
  }
}

// ---------------- out = tanh(pooled @ Wo1 + bo1): 64 rows x 12 col-chunks ----------------
__global__ __launch_bounds__(256) void k_tanh(const float* __restrict__ pooled,
                                              const void* __restrict__ Wo1,
                                              const void* __restrict__ bo1,
                                              const unsigned short* __restrict__ em16,
                                              float* __restrict__ outrow) {
  __shared__ float part[4][64];
  int f32 = detect_f32(em16);
  int t = threadIdx.x;
  int row = blockIdx.x / 12, chunk = blockIdx.x % 12;
  int col = chunk * 64 + (t & 63), kw = t >> 6;
  const float* pr = pooled + (size_t)row * HID + kw * 192;
  float acc = 0.f;
  if (f32) {
    const float* W = (const float*)Wo1 + (size_t)(kw * 192) * HID + col;
#pragma unroll 4
    for (int i = 0; i < 192; i++) acc += pr[i] * W[(size_t)i * HID];
  } else {
    const BF* W = (const BF*)Wo1 + (size_t)(kw * 192) * HID + col;
#pragma unroll 4
    for (int i = 0; i < 192; i++) acc += pr[i] * b2f(W[(size_t)i * HID]);
  }
  part[kw][t & 63] = acc;
  __syncthreads();
  if (t < 64) {
    float s = part[0][t] + part[1][t] + part[2][t] + part[3][t] + ldf(bo1, chunk * 64 + t, f32);
    outrow[(size_t)row * HID + chunk * 64 + t] = tanhf(s);
  }
}

// ---------------- fused: blocks 0-63 logits/d_out ; blocks 64-127 SimCSE rows ----------------
__global__ __launch_bounds__(256) void k_postsim(const float* __restrict__ outrow,
                                                 const void* __restrict__ Wo2,
                                                 const void* __restrict__ bo2,
                                                 const unsigned short* __restrict__ em16,
                                                 float* __restrict__ logitsbuf,
                                                 float* __restrict__ simbuf,
                                                 void* __restrict__ d_out) {
  __shared__ float s_buf[HID];
  int t = threadIdx.x;
  if (blockIdx.x < 64) {  // ---- post: logits row b ----
    int f32 = detect_f32(em16);
    int b = blockIdx.x;
    for (int k = t; k < HID; k += 256) s_buf[k] = outrow[(size_t)b * HID + k];
    __syncthreads();
    if (t < 10) {
      float acc = ldf(bo2, t, f32);
#pragma unroll 8
      for (int k = 0; k < HID; k++) acc += s_buf[k] * ldf(Wo2, (size_t)k * 10 + t, f32);
      logitsbuf[b * 10 + t] = acc;
      if (b < 32) {
        if (f32) ((float*)d_out)[1 + b * 10 + t] = acc;
        else ((BF*)d_out)[1 + b * 10 + t] = __float2bfloat16(acc);
      }
    }
  } else {  // ---- sim row r, norms computed inline ----
    int r = blockIdx.x - 64;
    int ir = (r & 1) * 32 + (r >> 1);
    for (int k = t; k < HID; k += 256) s_buf[k] = outrow[(size_t)ir * HID + k];
    __syncthreads();
    int lane = t & 63, w = t >> 6;
    // every wave computes nr redundantly via lane partition k = lane + 64*i
    float n2 = 0.f;
#pragma unroll
    for (int i = 0; i < 12; i++) { float v = s_buf[lane + 64 * i]; n2 += v * v; }
#pragma unroll
    for (int d = 32; d >= 1; d >>= 1) n2 += __shfl_xor(n2, d, 64);
    float nr = fmaxf(sqrtf(n2), 1e-8f);
    for (int j = 0; j < 16; j++) {
      int qq = 4 * j + w;
      int iq = (qq & 1) * 32 + (qq >> 1);
      const float* pq = outrow + (size_t)iq * HID;
      float s = 0.f, q2 = 0.f;
#pragma unroll
      for (int i = 0; i < 12; i++) {
        float qv = pq[lane + 64 * i];
        s += s_buf[lane + 64 * i] * qv;
        q2 += qv * qv;
      }
#pragma unroll
      for (int d = 32; d >= 1; d >>= 1) {
        s += __shfl_xor(s, d, 64);
        q2 += __shfl_xor(q2, d, 64);
      }
      if (lane == 0) {
        float nq = fmaxf(sqrtf(q2), 1e-8f);
        float tot = s / (nr * nq);
        if (qq == r) tot -= 1e12f;
        simbuf[r * 64 + qq] = tot * 20.f;
      }
    }
  }
}

// ---------------- final losses ----------------
__global__ void k_loss(const float* __restrict__ logitsbuf, const int* __restrict__ label,
                       const float* __restrict__ simbuf,
                       const unsigned short* __restrict__ em16,
                       void* __restrict__ d_out) {
  __shared__ float s_nll[64], s_sl[64];
  int f32 = detect_f32(em16);
  int t = threadIdx.x;  // 64 threads
  {
    const float* lg = logitsbuf + t * 10;
    float m = lg[0];
    for (int j = 1; j < 10; j++) m = fmaxf(m, lg[j]);
    float s = 0.f;
    for (int j = 0; j < 10; j++) s += expf(lg[j] - m);
    s_nll[t] = -(lg[label[t & 31]] - (m + logf(s)));
  }
  {
    const float* row = simbuf + t * 64;
    float m = row[0];
    for (int q = 1; q < 64; q++) m = fmaxf(m, row[q]);
    float s = 0.f;
    for (int q = 0; q < 64; q++) s += expf(row[q] - m);
    s_sl[t] = -(row[t ^ 1] - (m + logf(s)));
  }
  __syncthreads();
  if (t == 0) {
    float l = 0.f, ol = 0.f, sl = 0.f;
    for (int i = 0; i < 32; i++) { l += s_nll[i]; ol += s_nll[32 + i]; }
    for (int i = 0; i < 64; i++) sl += s_sl[i];
    float tot = l / 32.f + ol / 32.f + sl / 64.f;
    if (f32) ((float*)d_out)[0] = tot;
    else ((BF*)d_out)[0] = __float2bfloat16(tot);
  }
}

extern "C" void kernel_launch(void* const* d_in, const int* in_sizes, int n_in,
                              void* d_out, int out_size, void* d_ws, size_t ws_size,
                              hipStream_t stream) {
  const int* src   = (const int*)d_in[0];
  const int* oth   = (const int*)d_in[1];
  const int* label = (const int*)d_in[2];
  const void* feat = d_in[3];
  const void* em   = d_in[4];
  const void* W1   = d_in[5];
  const void* as1  = d_in[6];
  const void* ad1  = d_in[7];
  const void* b1   = d_in[8];
  const void* W2   = d_in[9];
  const void* as2  = d_in[10];
  const void* ad2  = d_in[11];
  const void* b2   = d_in[12];
  const void* Wo1  = d_in[13];
  const void* bo1  = d_in[14];
  const void* Wo2  = d_in[15];
  const void* bo2  = d_in[16];
  const unsigned short* em16 = (const unsigned short*)em;

  float* ws = (float*)d_ws;
  float* h1        = ws;                 // 524288
  float* a_s1      = ws + 524288;        // 32768
  float* a_d1      = ws + 557056;        // 32768
  float* v_s       = ws + 589824;        // 32
  float* v_d       = ws + 589856;        // 32
  float* x2        = ws + 589888;        // 1048576
  float* a_s2      = ws + 1638464;       // 32768
  float* a_d2      = ws + 1671232;       // 32768
  float* pooled    = ws + 1704000;       // 49152
  float* outrow    = ws + 1753152;       // 49152
  float* logitsbuf = ws + 1802304;       // 640
  float* simbuf    = ws + 1803008;       // 4096
  unsigned short* w1t = (unsigned short*)(ws + 1807104);  // 24576 ushorts

  k_prep<<<98, 256, 0, stream>>>(W1, W2, as2, ad2, em16, w1t, v_s, v_d);
  k_h1<<<256, 256, 0, stream>>>(feat, w1t, as1, ad1, em16, h1, a_s1, a_d1);
  k_x2<<<4096, 256, 0, stream>>>(h1, a_s1, a_d1, src, oth, em, b1, v_s, v_d, x2, a_s2, a_d2);
  k_pool<<<64, 256, 0, stream>>>(x2, a_s2, a_d2, W2, b2, em16, pooled);
  k_tanh<<<768, 256, 0, stream>>>(pooled, Wo1, bo1, em16, outrow);
  k_postsim<<<128, 256, 0, stream>>>(outrow, Wo2, bo2, em16, logitsbuf, simbuf, d_out);
  k_loss<<<1, 64, 0, stream>>>(logitsbuf, label, simbuf, em16, d_out);
}